// Round 22
// baseline (566.353 us; speedup 1.0000x reference)
//
#include <hip/hip_runtime.h>
#include <hip/hip_bf16.h>

typedef __hip_bfloat16 bf16;

#define BB 2
#define SS 1024
#define DD 1024
#define GG 8
#define HH 2
#define HDIM 64
#define EE 8
#define KTOP 2
#define FFD 4096
#define NTOK (BB*SS)          // 2048
#define NSEL (NTOK*KTOP)      // 4096

typedef __attribute__((ext_vector_type(8))) short bf16x8v;
typedef __attribute__((ext_vector_type(4))) float f32x4;
typedef __attribute__((ext_vector_type(4))) unsigned int u32x4;

union FragU { uint32_t u[4]; bf16x8v v; };
union FragQ { u32x4 q; bf16x8v v; };

__device__ __forceinline__ float b2f(bf16 v){ return __bfloat162float(v); }
__device__ __forceinline__ bf16  f2b(float v){ return __float2bfloat16(v); }
__device__ __forceinline__ uint32_t f2bu(float f){
  union { bf16 b; unsigned short u; } c; c.b = __float2bfloat16(f); return (uint32_t)c.u;
}
__device__ __forceinline__ uint32_t packbf(float lo, float hi){
  return f2bu(lo) | (f2bu(hi) << 16);
}

// ---------------- RMSNorm -> f32 out ----------------
__global__ void rmsnorm_kernel(const float* __restrict__ x, const float* __restrict__ w,
                               float* __restrict__ out){
  int row = blockIdx.x, tid = threadIdx.x;
  const float* xr = x + (size_t)row * DD;
  float v0 = xr[tid];
  float v1 = xr[tid+256];
  float v2 = xr[tid+512];
  float v3 = xr[tid+768];
  float ss = v0*v0+v1*v1+v2*v2+v3*v3;
  for (int off=32; off; off>>=1) ss += __shfl_down(ss, off);
  __shared__ float red[4];
  if ((tid&63)==0) red[tid>>6]=ss;
  __syncthreads();
  float inv = rsqrtf((red[0]+red[1]+red[2]+red[3])*(1.0f/DD) + 1e-6f);
  float* orow = out + (size_t)row*DD;
  orow[tid]     = v0*inv*w[tid];
  orow[tid+256] = v1*inv*w[tid+256];
  orow[tid+512] = v2*inv*w[tid+512];
  orow[tid+768] = v3*inv*w[tid+768];
}

// ---------------- RMSNorm -> bf16 out (norm1, feeds qkv MFMA) ----------------
__global__ void rmsnorm_b16_kernel(const float* __restrict__ x, const float* __restrict__ w,
                                   bf16* __restrict__ out){
  int row = blockIdx.x, tid = threadIdx.x;
  const float* xr = x + (size_t)row * DD;
  float v0 = xr[tid];
  float v1 = xr[tid+256];
  float v2 = xr[tid+512];
  float v3 = xr[tid+768];
  float ss = v0*v0+v1*v1+v2*v2+v3*v3;
  for (int off=32; off; off>>=1) ss += __shfl_down(ss, off);
  __shared__ float red[4];
  if ((tid&63)==0) red[tid>>6]=ss;
  __syncthreads();
  float inv = rsqrtf((red[0]+red[1]+red[2]+red[3])*(1.0f/DD) + 1e-6f);
  bf16* orow = out + (size_t)row*DD;
  orow[tid]     = f2b(v0*inv*w[tid]);
  orow[tid+256] = f2b(v1*inv*w[tid+256]);
  orow[tid+512] = f2b(v2*inv*w[tid+512]);
  orow[tid+768] = f2b(v3*inv*w[tid+768]);
}

// ---------------- QKV projection (MFMA GEMM M=2048,N=2048,K=1024) ----------------
// Transposed LDS: Bt[col][kp], b128 frag reads. (round-14 proven form)
__global__ void __launch_bounds__(256) qkv_mfma(const bf16* __restrict__ hxb,
      const float* __restrict__ Wq, const float* __restrict__ Wk, const float* __restrict__ Wv,
      float* __restrict__ q, float* __restrict__ k, bf16* __restrict__ vb){
  int mtile = blockIdx.x;
  int nt = blockIdx.y;
  int g = nt >> 2, sub = nt & 3;
  const float* wsrc; int ld;
  if (sub < 2){ wsrc = Wq + (size_t)g*DD*128 + sub*64; ld = 128; }
  else if (sub == 2){ wsrc = Wk + (size_t)g*DD*64; ld = 64; }
  else { wsrc = Wv + (size_t)g*DD*64; ld = 64; }

  __shared__ __attribute__((aligned(16))) uint32_t Bt[64][20];
  int tid = threadIdx.x;
  int w = tid >> 6, l = tid & 63, lg = l >> 4, lr = l & 15;
  int wm = (w >> 1)*32, wn = (w & 1)*32;

  const bf16* arow[2];
  #pragma unroll
  for (int mf=0; mf<2; mf++)
    arow[mf] = hxb + (size_t)(mtile*64 + wm + mf*16 + lr)*DD;

  int scol = tid & 63, skp = tid >> 6;

  f32x4 acc[2][2];
  #pragma unroll
  for (int mf=0;mf<2;mf++)
    #pragma unroll
    for (int nf=0;nf<2;nf++) acc[mf][nf] = (f32x4){0,0,0,0};

  float gld[8];
  #pragma unroll
  for (int jj=0;jj<8;jj++) gld[jj] = wsrc[(size_t)(8*skp + jj)*ld + scol];

  for (int kb=0; kb<DD; kb+=32){
    __syncthreads();
    uint32_t pk[4];
    #pragma unroll
    for (int j2=0;j2<4;j2++) pk[j2] = packbf(gld[2*j2], gld[2*j2+1]);
    *(u32x4*)&Bt[scol][4*skp] = (u32x4){pk[0],pk[1],pk[2],pk[3]};
    __syncthreads();
    if (kb + 32 < DD){
      #pragma unroll
      for (int jj=0;jj<8;jj++) gld[jj] = wsrc[(size_t)(kb + 32 + 8*skp + jj)*ld + scol];
    }
    bf16x8v af[2];
    #pragma unroll
    for (int mf=0;mf<2;mf++)
      af[mf] = *(const bf16x8v*)(arow[mf] + kb + lg*8);
    #pragma unroll
    for (int nf=0;nf<2;nf++){
      FragQ bfr;
      bfr.q = *(const u32x4*)&Bt[wn + nf*16 + lr][lg*4];
      #pragma unroll
      for (int mf=0;mf<2;mf++)
        acc[mf][nf] = __builtin_amdgcn_mfma_f32_16x16x32_bf16(af[mf], bfr.v, acc[mf][nf], 0,0,0);
    }
  }
  #pragma unroll
  for (int mf=0;mf<2;mf++){
    #pragma unroll
    for (int nf=0;nf<2;nf++){
      #pragma unroll
      for (int r=0;r<4;r++){
        int token = mtile*64 + wm + mf*16 + lg*4 + r;
        int b = token >> 10, s = token & (SS-1);
        int c = wn + nf*16 + lr;
        float val = acc[mf][nf][r];
        if (sub < 2)       q[(((size_t)(b*GG+g)*HH + sub)*SS + s)*HDIM + c] = val;
        else if (sub == 2) k[(((size_t)(b*GG+g))*SS + s)*HDIM + c] = val;
        else               vb[(((size_t)(b*GG+g))*SS + s)*HDIM + c] = f2b(val);
      }
    }
  }
}

// ---------------- RoPE f32 -> bf16 ----------------
__global__ void rope_cast_kernel(const float* __restrict__ pin, bf16* __restrict__ pout, int nrows){
  int idx = blockIdx.x*256 + threadIdx.x;
  if (idx >= nrows*32) return;
  int r = idx >> 5, i = idx & 31;
  int s = r & (SS-1);
  float inv = expf(-9.210340371976184f * (float)i / 32.0f); // 10000^(-i/32)
  float ang = (float)s * inv;
  float sn = sinf(ang), cs = cosf(ang);
  const float* row = pin + (size_t)r * HDIM;
  float a = row[i], b = row[i+32];
  pout[(size_t)r*HDIM + i]      = f2b(a*cs - b*sn);
  pout[(size_t)r*HDIM + i + 32] = f2b(a*sn + b*cs);
}

// ---------------- Flash attention (MFMA, causal) + residual -> x1 ----------------
__global__ void __launch_bounds__(256) attn_mfma(
    const bf16* __restrict__ qb, const bf16* __restrict__ kb, const bf16* __restrict__ vb,
    const float* __restrict__ x, float* __restrict__ x1){
  int qt = blockIdx.x;
  int bh = blockIdx.y;
  int b = bh >> 4, gh = bh & 15;
  int bg = b*GG + (gh >> 1);
  int q0 = qt * 64;

  int tid = threadIdx.x;
  int w = tid >> 6, l = tid & 63, lg = l >> 4, lr = l & 15;

  __shared__ uint32_t Vp[32][68];
  __shared__ uint32_t Plu[4][16][33];

  const bf16* qbase = qb + ((size_t)bh*SS + q0 + w*16 + lr)*HDIM;
  bf16x8v qfr[2];
  qfr[0] = *(const bf16x8v*)(qbase + lg*8);
  qfr[1] = *(const bf16x8v*)(qbase + 32 + lg*8);

  f32x4 O[4];
  #pragma unroll
  for (int i=0;i<4;i++) O[i] = (f32x4){0,0,0,0};
  float mrow[4] = {-3e38f,-3e38f,-3e38f,-3e38f};
  float lrow[4] = {0.f,0.f,0.f,0.f};

  const bf16* kbg = kb + (size_t)bg*SS*HDIM;
  const unsigned short* vbg = (const unsigned short*)(vb + (size_t)bg*SS*HDIM);

  int c44 = (tid & 15)*4;
  int kpq = tid >> 4;

  for (int t=0; t<=qt; t++){
    int kv0 = t*64;
    __syncthreads();
    #pragma unroll
    for (int it=0; it<2; it++){
      int kp = kpq + it*16;
      const unsigned short* r0 = vbg + (size_t)(kv0 + 2*kp)*HDIM + c44;
      ushort4 a = *(const ushort4*)r0;
      ushort4 bq = *(const ushort4*)(r0 + HDIM);
      Vp[kp][c44+0] = (uint32_t)a.x | ((uint32_t)bq.x<<16);
      Vp[kp][c44+1] = (uint32_t)a.y | ((uint32_t)bq.y<<16);
      Vp[kp][c44+2] = (uint32_t)a.z | ((uint32_t)bq.z<<16);
      Vp[kp][c44+3] = (uint32_t)a.w | ((uint32_t)bq.w<<16);
    }
    __syncthreads();

    f32x4 sacc[4];
    #pragma unroll
    for (int nf=0;nf<4;nf++){
      sacc[nf] = (f32x4){0,0,0,0};
      const bf16* kr = kbg + (size_t)(kv0 + nf*16 + lr)*HDIM + lg*8;
      bf16x8v kf0 = *(const bf16x8v*)kr;
      bf16x8v kf1 = *(const bf16x8v*)(kr + 32);
      sacc[nf] = __builtin_amdgcn_mfma_f32_16x16x32_bf16(qfr[0], kf0, sacc[nf], 0,0,0);
      sacc[nf] = __builtin_amdgcn_mfma_f32_16x16x32_bf16(qfr[1], kf1, sacc[nf], 0,0,0);
    }

    bool diag = (t == qt);
    float p[4][4];
    float rmax[4] = {-3e38f,-3e38f,-3e38f,-3e38f};
    #pragma unroll
    for (int nf=0;nf<4;nf++){
      #pragma unroll
      for (int r=0;r<4;r++){
        float s = sacc[nf][r]*0.125f;
        if (diag && (nf*16+lr > w*16+lg*4+r)) s = -3e38f;
        p[nf][r] = s;
        rmax[r] = fmaxf(rmax[r], s);
      }
    }
    #pragma unroll
    for (int r=0;r<4;r++){
      #pragma unroll
      for (int mm=1; mm<16; mm<<=1) rmax[r] = fmaxf(rmax[r], __shfl_xor(rmax[r], mm));
      float mn = fmaxf(mrow[r], rmax[r]);
      float resc = __expf(mrow[r]-mn);
      mrow[r] = mn;
      float rsum = 0.f;
      #pragma unroll
      for (int nf=0;nf<4;nf++){
        float e = __expf(p[nf][r]-mn);
        p[nf][r] = e;
        rsum += e;
      }
      #pragma unroll
      for (int mm=1; mm<16; mm<<=1) rsum += __shfl_xor(rsum, mm);
      lrow[r] = lrow[r]*resc + rsum;
      O[0][r]*=resc; O[1][r]*=resc; O[2][r]*=resc; O[3][r]*=resc;
    }

    #pragma unroll
    for (int nf=0;nf<4;nf++){
      #pragma unroll
      for (int r=0;r<4;r++){
        float pnbr = __shfl_xor(p[nf][r], 1);
        if ((lr & 1) == 0)
          Plu[w][lg*4+r][(nf*16+lr)>>1] = packbf(p[nf][r], pnbr);
      }
    }

    #pragma unroll
    for (int kc=0;kc<2;kc++){
      FragU pa;
      #pragma unroll
      for (int jp=0;jp<4;jp++)
        pa.u[jp] = Plu[w][lr][kc*16 + lg*4 + jp];
      #pragma unroll
      for (int nf=0;nf<4;nf++){
        FragU vf;
        #pragma unroll
        for (int jp=0;jp<4;jp++) vf.u[jp] = Vp[kc*16 + lg*4 + jp][nf*16 + lr];
        O[nf] = __builtin_amdgcn_mfma_f32_16x16x32_bf16(pa.v, vf.v, O[nf], 0,0,0);
      }
    }
  }

  #pragma unroll
  for (int r=0;r<4;r++){
    int s = q0 + w*16 + lg*4 + r;
    float inv = 1.f/fmaxf(lrow[r], 1e-30f);
    size_t rowo = ((size_t)(b*SS + s))*DD + gh*HDIM;
    #pragma unroll
    for (int nf=0;nf<4;nf++){
      size_t oi = rowo + nf*16 + lr;
      x1[oi] = x[oi] + O[nf][r]*inv;
    }
  }
}

// ---------------- Router: logits, softmax, top-2; probs to buffer (NO atomics) ----------------
__global__ void router_kernel(const float* __restrict__ h2, const float* __restrict__ rw,
                              int* __restrict__ topi, float* __restrict__ topv,
                              float* __restrict__ probs){
  int token = blockIdx.x, tid = threadIdx.x;
  const float* hr = h2 + (size_t)token * DD;
  float part[EE];
  #pragma unroll
  for (int e=0;e<EE;e++) part[e]=0.f;
  for (int d = tid; d < DD; d += 256) {
    float hv = hr[d];
    #pragma unroll
    for (int e=0;e<EE;e++) part[e] += hv * rw[d*EE+e];
  }
  #pragma unroll
  for (int e=0;e<EE;e++)
    for (int off=32; off; off>>=1) part[e] += __shfl_down(part[e], off);
  __shared__ float red[4][EE];
  if ((tid&63)==0){
    #pragma unroll
    for (int e=0;e<EE;e++) red[tid>>6][e]=part[e];
  }
  __syncthreads();
  if (tid==0){
    float lg[EE];
    #pragma unroll
    for (int e=0;e<EE;e++) lg[e]=red[0][e]+red[1][e]+red[2][e]+red[3][e];
    float m = lg[0];
    #pragma unroll
    for (int e=1;e<EE;e++) m = fmaxf(m, lg[e]);
    float ex[EE], ssum=0.f;
    #pragma unroll
    for (int e=0;e<EE;e++){ ex[e]=expf(lg[e]-m); ssum+=ex[e]; }
    float p[EE];
    #pragma unroll
    for (int e=0;e<EE;e++){ p[e]=ex[e]/ssum; probs[token*EE+e]=p[e]; }
    int i1=0;
    for (int e=1;e<EE;e++) if (p[e]>p[i1]) i1=e;
    int i2=-1;
    for (int e=0;e<EE;e++) if (e!=i1 && (i2<0 || p[e]>p[i2])) i2=e;
    float g1=p[i1], g2=p[i2], gs=g1+g2;
    topi[token*2]=i1; topi[token*2+1]=i2;
    topv[token*2]=g1/gs; topv[token*2+1]=g2/gs;
  }
}

// ---------------- Stats: reduce probs -> sumP, topi -> counts (1 block) ----------------
__global__ void stats_kernel(const float* __restrict__ probs, const int* __restrict__ topi,
                             float* __restrict__ sumP, int* __restrict__ counts){
  int tid = threadIdx.x;      // 256
  float ls[EE];
  int lc[EE];
  #pragma unroll
  for (int e=0;e<EE;e++){ ls[e]=0.f; lc[e]=0; }
  for (int t = tid; t < NTOK; t += 256){
    const float* pr = probs + (size_t)t*EE;
    #pragma unroll
    for (int e=0;e<EE;e++) ls[e] += pr[e];
    lc[topi[2*t]]++;
    lc[topi[2*t+1]]++;
  }
  #pragma unroll
  for (int e=0;e<EE;e++){
    for (int off=32; off; off>>=1){
      ls[e] += __shfl_down(ls[e], off);
      lc[e] += __shfl_down(lc[e], off);
    }
  }
  __shared__ float rs[4][EE];
  __shared__ int   rc[4][EE];
  if ((tid&63)==0){
    #pragma unroll
    for (int e=0;e<EE;e++){ rs[tid>>6][e]=ls[e]; rc[tid>>6][e]=lc[e]; }
  }
  __syncthreads();
  if (tid==0){
    #pragma unroll
    for (int e=0;e<EE;e++){
      sumP[e]   = rs[0][e]+rs[1][e]+rs[2][e]+rs[3][e];
      counts[e] = rc[0][e]+rc[1][e]+rc[2][e]+rc[3][e];
    }
  }
}

// ---------------- Deterministic routing fill + tile-descriptor table ----------------
__global__ void fill_kernel(const int* __restrict__ topi, const float* __restrict__ topv,
                            const int* __restrict__ counts, int* __restrict__ offs,
                            int* __restrict__ tok_list, float* __restrict__ gate_list,
                            int* __restrict__ tdesc, int* __restrict__ ndesc){
  int tid = threadIdx.x;        // 512 = 8 waves
  int w = tid >> 6, lane = tid & 63;
  if (tid < EE){
    int o = 0;
    for (int e=0;e<tid;e++) o += counts[e];
    offs[tid] = o;
  }
  if (tid == 0){
    int n = 0;
    for (int e=0;e<EE;e++){
      int t = (counts[e] + 255) >> 8;
      for (int m=0;m<t;m++) tdesc[n++] = e | (m << 8);
    }
    *ndesc = n;
  }
  int pos = 0;
  for (int e=0;e<w;e++) pos += counts[e];
  for (int j0=0; j0<NSEL; j0+=64){
    int j = j0 + lane;
    bool hit = (topi[j] == w);
    unsigned long long mask = __ballot(hit);
    if (hit){
      int idx = pos + __popcll(mask & ((1ull<<lane)-1ull));
      tok_list[idx] = j >> 1;
      gate_list[idx] = topv[j];
    }
    pos += __popcll(mask);
  }
}

// ---------------- Gather routed activations to bf16 A matrix ----------------
__global__ void gather_kernel(const float* __restrict__ h2, const int* __restrict__ tok_list,
                              bf16* __restrict__ Abuf){
  int i = blockIdx.x*256 + threadIdx.x;
  int pos = i >> 10, d = i & 1023;
  int tok = tok_list[pos];
  Abuf[(size_t)pos*DD + d] = f2b(h2[(size_t)tok*DD + d]);
}

// ---------------- MoE phase A (MFMA): hidden = silu(A@Wg)*(A@Wu) ----------------
// BM=256, BN=32, BK=64, transposed LDS [32][36], b128 frag reads.
// A-fragment ping-pong prefetch (afP/afQ): next step's A issued in stage phase,
// MFMAs consume resident registers (no inline A-load latency on critical path).
__global__ void __launch_bounds__(256, 2) moeA_mfma(const bf16* __restrict__ Abuf,
                            const float* __restrict__ wg, const float* __restrict__ wu,
                            bf16* __restrict__ hidden,
                            const int* __restrict__ counts, const int* __restrict__ offs,
                            const int* __restrict__ tdesc, const int* __restrict__ ndesc){
  int ti = blockIdx.y;
  if (ti >= *ndesc) return;
  int d = tdesc[ti];
  int e = d & 255, mtile = d >> 8;
  int cnt = counts[e];
  int ntile = blockIdx.x;          // 0..127
  int offs_e = offs[e];
  int ncol0 = ntile*32;

  __shared__ __attribute__((aligned(16))) uint32_t Bg[32][36];
  __shared__ __attribute__((aligned(16))) uint32_t Bu[32][36];

  int tid = threadIdx.x;
  int w = tid >> 6, l = tid & 63, lg = l >> 4, lr = l & 15;
  int wm = w*64;

  const bf16* arow[4];
  #pragma unroll
  for (int mf=0; mf<4; mf++){
    int slot = mtile*256 + wm + mf*16 + lr;
    if (slot >= cnt) slot = cnt - 1;
    arow[mf] = Abuf + (size_t)(offs_e + slot)*DD;
  }

  const float* wgb = wg + (size_t)e*DD*FFD + ncol0;
  const float* wub = wu + (size_t)e*DD*FFD + ncol0;
  int scol = tid & 31, skp4 = tid >> 5;   // col 0..31, 8 k-groups of 8 rows each

  f32x4 acc_g[4][2], acc_u[4][2];
  #pragma unroll
  for (int mf=0; mf<4; mf++)
    #pragma unroll
    for (int nf=0; nf<2; nf++){ acc_g[mf][nf] = (f32x4){0,0,0,0}; acc_u[mf][nf] = (f32x4){0,0,0,0}; }

  float gld[8], uld[8];
  #pragma unroll
  for (int jj=0;jj<8;jj++){
    gld[jj] = wgb[(size_t)(8*skp4 + jj)*FFD + scol];
    uld[jj] = wub[(size_t)(8*skp4 + jj)*FFD + scol];
  }

  // A-fragment prologue for step kb=0: afP[h*4+mf]
  bf16x8v afP[8], afQ[8];
  #pragma unroll
  for (int h=0; h<2; h++)
    #pragma unroll
    for (int mf=0; mf<4; mf++)
      afP[h*4+mf] = *(const bf16x8v*)(arow[mf] + h*32 + lg*8);

  for (int kb=0; kb<DD; kb+=128){
    // ======== step 0: k rows [kb, kb+64), A = afP ========
    __syncthreads();
    {
      uint32_t pg[4], pu[4];
      #pragma unroll
      for (int j2=0;j2<4;j2++){
        pg[j2] = packbf(gld[2*j2], gld[2*j2+1]);
        pu[j2] = packbf(uld[2*j2], uld[2*j2+1]);
      }
      *(u32x4*)&Bg[scol][4*skp4] = (u32x4){pg[0],pg[1],pg[2],pg[3]};
      *(u32x4*)&Bu[scol][4*skp4] = (u32x4){pu[0],pu[1],pu[2],pu[3]};
    }
    __syncthreads();
    // stage phase for next step (kb+64): B loads + A prefetch into afQ
    {
      #pragma unroll
      for (int jj=0;jj<8;jj++){
        gld[jj] = wgb[(size_t)(kb + 64 + 8*skp4 + jj)*FFD + scol];
        uld[jj] = wub[(size_t)(kb + 64 + 8*skp4 + jj)*FFD + scol];
      }
      #pragma unroll
      for (int h=0; h<2; h++)
        #pragma unroll
        for (int mf=0; mf<4; mf++)
          afQ[h*4+mf] = *(const bf16x8v*)(arow[mf] + kb + 64 + h*32 + lg*8);
    }
    #pragma unroll
    for (int h=0; h<2; h++){
      #pragma unroll
      for (int nf=0; nf<2; nf++){
        int col = nf*16 + lr;
        FragQ fg, fu;
        fg.q = *(const u32x4*)&Bg[col][h*16 + lg*4];
        fu.q = *(const u32x4*)&Bu[col][h*16 + lg*4];
        #pragma unroll
        for (int mf=0; mf<4; mf++){
          acc_g[mf][nf] = __builtin_amdgcn_mfma_f32_16x16x32_bf16(afP[h*4+mf], fg.v, acc_g[mf][nf], 0,0,0);
          acc_u[mf][nf] = __builtin_amdgcn_mfma_f32_16x16x32_bf16(afP[h*4+mf], fu.v, acc_u[mf][nf], 0,0,0);
        }
      }
    }
    // ======== step 1: k rows [kb+64, kb+128), A = afQ ========
    __syncthreads();
    {
      uint32_t pg[4], pu[4];
      #pragma unroll
      for (int j2=0;j2<4;j2++){
        pg[j2] = packbf(gld[2*j2], gld[2*j2+1]);
        pu[j2] = packbf(uld[2*j2], uld[2*j2+1]);
      }
      *(u32x4*)&Bg[scol][4*skp4] = (u32x4){pg[0],pg[1],pg[2],pg[3]};
      *(u32x4*)&Bu[scol][4*skp4] = (u32x4){pu[0],pu[1],pu[2],pu[3]};
    }
    __syncthreads();
    if (kb + 128 < DD){
      #pragma unroll
      for (int jj=0;jj<8;jj++){
        gld[jj] = wgb[(size_t)(kb + 128 + 8*skp4 + jj)*FFD + scol];
        uld[jj] = wub[(size_t)(kb + 128 + 8*skp4 + jj)*FFD + scol];
      }
      #pragma unroll
      for (int h=0; h<2; h++)
        #pragma unroll
        for (int mf=0; mf<4; mf++)
          afP[h*4+mf] = *(const bf16x8v*)(arow[mf] + kb + 128 + h*32 + lg*8);
    }
    #pragma unroll
    for (int h=0; h<2; h++){
      #pragma unroll
      for (int nf=0; nf<2; nf++){
        int col = nf*16 + lr;
        FragQ fg, fu;
        fg.q = *(const u32x4*)&Bg[col][h*16 + lg*4];
        fu.q = *(const u32x4*)&Bu[col][h*16 + lg*4];
        #pragma unroll
        for (int mf=0; mf<4; mf++){
          acc_g[mf][nf] = __builtin_amdgcn_mfma_f32_16x16x32_bf16(afQ[h*4+mf], fg.v, acc_g[mf][nf], 0,0,0);
          acc_u[mf][nf] = __builtin_amdgcn_mfma_f32_16x16x32_bf16(afQ[h*4+mf], fu.v, acc_u[mf][nf], 0,0,0);
        }
      }
    }
  }
  #pragma unroll
  for (int mf=0; mf<4; mf++){
    #pragma unroll
    for (int ri=0; ri<4; ri++){
      int slot = mtile*256 + wm + mf*16 + lg*4 + ri;
      if (slot < cnt){
        bf16* hrow = hidden + (size_t)(offs_e + slot)*FFD + ncol0;
        #pragma unroll
        for (int nf=0; nf<2; nf++){
          float gv = acc_g[mf][nf][ri];
          float uv = acc_u[mf][nf][ri];
          float act = gv / (1.f + expf(-gv)) * uv;
          hrow[nf*16 + lr] = f2b(act);
        }
      }
    }
  }
}

// ---------------- MoE phase B (MFMA): moe_out += gate * hidden @ Wd ----------------
// BM=256, BN=128, 4-way K-split, transposed LDS, float4-vectorized weight staging.
__global__ void __launch_bounds__(256, 2) moeB_mfma(const bf16* __restrict__ hidden,
                            const float* __restrict__ wd, float* __restrict__ moe_out,
                            const int* __restrict__ counts, const int* __restrict__ offs,
                            const int* __restrict__ tok_list, const float* __restrict__ gate_list,
                            const int* __restrict__ tdesc, const int* __restrict__ ndesc){
  int ti = blockIdx.y;
  if (ti >= *ndesc) return;
  int d = tdesc[ti];
  int e = d & 255, mtile = d >> 8;
  int cnt = counts[e];
  int ntile = blockIdx.x & 7;
  int kchunk = blockIdx.x >> 3;
  int offs_e = offs[e];
  int ncol0 = ntile*128;
  int kb0 = kchunk*1024;

  __shared__ __attribute__((aligned(16))) uint32_t Bd[128][20];

  int tid = threadIdx.x;
  int w = tid >> 6, l = tid & 63, lg = l >> 4, lr = l & 15;
  int wm = w*64;

  const bf16* arow[4];
  #pragma unroll
  for (int mf=0; mf<4; mf++){
    int slot = mtile*256 + wm + mf*16 + lr;
    if (slot >= cnt) slot = cnt - 1;
    arow[mf] = hidden + (size_t)(offs_e + slot)*FFD + kb0;
  }

  const float* wdb = wd + (size_t)e*FFD*DD + (size_t)kb0*DD + ncol0;
  int skp8 = tid >> 5;                // 0..7 (handles kpairs skp8 and skp8+8)
  int scol4 = (tid & 31) * 4;         // 0..124 column group

  f32x4 acc[4][8];
  #pragma unroll
  for (int mf=0; mf<4; mf++)
    #pragma unroll
    for (int nf=0; nf<8; nf++) acc[mf][nf] = (f32x4){0,0,0,0};

  float4 da0, da1, db0, db1;
  da0 = *(const float4*)&wdb[(size_t)(2*skp8)*DD + scol4];
  da1 = *(const float4*)&wdb[(size_t)(2*skp8+1)*DD + scol4];
  db0 = *(const float4*)&wdb[(size_t)(2*skp8+16)*DD + scol4];
  db1 = *(const float4*)&wdb[(size_t)(2*skp8+17)*DD + scol4];

  for (int kb=0; kb<1024; kb+=32){
    __syncthreads();
    Bd[scol4+0][skp8]   = packbf(da0.x, da1.x);
    Bd[scol4+1][skp8]   = packbf(da0.y, da1.y);
    Bd[scol4+2][skp8]   = packbf(da0.z, da1.z);
    Bd[scol4+3][skp8]   = packbf(da0.w, da1.w);
    Bd[scol4+0][skp8+8] = packbf(db0.x, db1.x);
    Bd[scol4+1][skp8+8] = packbf(db0.y, db1.y);
    Bd[scol4+2][skp8+8] = packbf(db0.z, db1.z);
    Bd[scol4+3][skp8+8] = packbf(db0.w, db1.w);
    __syncthreads();
    if (kb + 32 < 1024){
      da0 = *(const float4*)&wdb[(size_t)(kb + 32 + 2*skp8)*DD + scol4];
      da1 = *(const float4*)&wdb[(size_t)(kb + 32 + 2*skp8+1)*DD + scol4];
      db0 = *(const float4*)&wdb[(size_t)(kb + 32 + 2*skp8+16)*DD + scol4];
      db1 = *(const float4*)&wdb[(size_t)(kb + 32 + 2*skp8+17)*DD + scol4];
    }
    bf16x8v afr[4];
    #pragma unroll
    for (int mf=0; mf<4; mf++)
      afr[mf] = *(const bf16x8v*)(arow[mf] + kb + lg*8);
    #pragma unroll
    for (int nf=0; nf<8; nf++){
      int col = nf*16 + lr;
      FragQ fd;
      fd.q = *(const u32x4*)&Bd[col][lg*4];
      #pragma unroll
      for (int mf=0; mf<4; mf++)
        acc[mf][nf] = __builtin_amdgcn_mfma_f32_16x16x32_bf16(afr[mf], fd.v, acc[mf][nf], 0,0,0);
    }
  }
  #pragma unroll
  for (int mf=0; mf<4; mf++){
    #pragma unroll
    for (int ri=0; ri<4; ri++){
      int slot = mtile*256 + wm + mf*16 + lg*4 + ri;
      if (slot < cnt){
        int pos = offs_e + slot;
        int tok = tok_list[pos];
        float gate = gate_list[pos];
        float* orow = moe_out + (size_t)tok*DD + ncol0;
        #pragma unroll
        for (int nf=0; nf<8; nf++)
          atomicAdd(&orow[nf*16 + lr], gate * acc[mf][nf][ri]);
      }
    }
  }
}

// ---------------- Final: out = x1 + moe_out, + aux ----------------
__global__ void final_kernel(const float* __restrict__ x1, const float* __restrict__ moe,
                             float* __restrict__ out,
                             const int* __restrict__ counts, const float* __restrict__ sumP){
  int i = blockIdx.x*256 + threadIdx.x;
  if (i < BB*SS*DD) {
    out[i] = x1[i] + moe[i];
  } else if (i == BB*SS*DD) {
    float aux = 0.f;
    for (int e=0;e<EE;e++)
      aux += ((float)counts[e] / (float)(BB*SS*KTOP)) * (sumP[e] / (float)(BB*SS));
    out[i] = aux * (float)EE;
  }
}

extern "C" void kernel_launch(void* const* d_in, const int* in_sizes, int n_in,
                              void* d_out, int out_size, void* d_ws, size_t ws_size,
                              hipStream_t stream) {
  const float* x        = (const float*)d_in[0];
  const float* norm1_w  = (const float*)d_in[1];
  const float* Wq       = (const float*)d_in[2];
  const float* Wk       = (const float*)d_in[3];
  const float* Wv       = (const float*)d_in[4];
  const float* norm2_w  = (const float*)d_in[5];
  const float* router_w = (const float*)d_in[6];
  const float* w_gate   = (const float*)d_in[7];
  const float* w_up     = (const float*)d_in[8];
  const float* w_down   = (const float*)d_in[9];
  float* out = (float*)d_out;

  float* ws = (float*)d_ws;
  // word offsets (f32 words) — total 20,987,936 words = 83.95 MB (proven footprint)
  bf16*  hxb     = (bf16*)ws;                     // [0 .. 1,048,576)        2048x1024 bf16
  float* qf      = ws + 1048576;                  // [1,048,576 .. 3,145,728)  32768x64 f32
  float* kf      = ws + 3145728;                  // [3,145,728 .. 4,194,304)  16384x64 f32
  bf16*  qbb     = (bf16*)(ws + 4194304);         // [4,194,304 .. 5,242,880)  32768x64 bf16
  bf16*  kbb     = (bf16*)(ws + 5242880);         // [5,242,880 .. 5,767,168)  16384x64 bf16
  bf16*  vbb     = (bf16*)(ws + 5767168);         // [5,767,168 .. 6,291,456)  16384x64 bf16
  float* x1      = ws + 6291456;                  // [6,291,456 .. 8,388,608)
  float* h2      = ws + 8388608;                  // [8,388,608 .. 10,485,760)
  float* moe_out = ws + 10485760;                 // [10,485,760 .. 12,582,912)
  int*   counts  = (int*)(ws + 12582912);         // 8
  float* sumP    = ws + 12582920;                 // 8
  int*   offs    = (int*)(ws + 12582928);         // 8 (+pad)
  int*   topi    = (int*)(ws + 12582944);         // 4096
  float* topv    = ws + 12587040;                 // 4096
  int*   tok_list= (int*)(ws + 12591136);         // 4096
  float* gate_list = ws + 12595232;               // 4096
  bf16*  hidden  = (bf16*)(ws + 12599328);        // 4096x4096 bf16 -> ends 20,987,936
  bf16*  Abuf    = (bf16*)ws;                     // words [0..2,097,152); aliases hxb+qf[:half], dead
  int*   tdesc   = (int*)(ws + 3145728);          // 24 ints in dead kf region
  int*   ndesc   = (int*)(ws + 3145728 + 24);     // 1 int
  float* probs   = ws + 3145728 + 32;             // 2048x8 f32 = 16384 words, in dead kf region

  hipMemsetAsync(moe_out, 0, (size_t)BB*SS*DD*sizeof(float), stream);

  // 1. norm1 -> bf16
  rmsnorm_b16_kernel<<<NTOK, 256, 0, stream>>>(x, norm1_w, hxb);
  // 2. qkv MFMA (writes f32 q/k, bf16 v)
  qkv_mfma<<<dim3(32, 32), 256, 0, stream>>>(hxb, Wq, Wk, Wv, qf, kf, vbb);
  // 3. rope + cast to bf16
  rope_cast_kernel<<<(BB*GG*HH*SS*32)/256, 256, 0, stream>>>(qf, qbb, BB*GG*HH*SS);
  rope_cast_kernel<<<(BB*GG*SS*32)/256, 256, 0, stream>>>(kf, kbb, BB*GG*SS);
  // 4. flash attention + residual
  attn_mfma<<<dim3(SS/64, BB*GG*HH), 256, 0, stream>>>(qbb, kbb, vbb, x, x1);
  // 5. norm2
  rmsnorm_kernel<<<NTOK, 256, 0, stream>>>(x1, norm2_w, h2);
  // 6. router (no atomics) + stats reduction + routing tables
  router_kernel<<<NTOK, 256, 0, stream>>>(h2, router_w, topi, topv, probs);
  stats_kernel<<<1, 256, 0, stream>>>(probs, topi, sumP, counts);
  fill_kernel<<<1, 512, 0, stream>>>(topi, topv, counts, offs, tok_list, gate_list, tdesc, ndesc);
  // 7. MoE (MFMA grouped GEMM, BM=256, compacted tile grid; moeA BN=32/BK=64 + A-ping-pong)
  gather_kernel<<<(NSEL*DD)/256, 256, 0, stream>>>(h2, tok_list, Abuf);
  moeA_mfma<<<dim3(128, 24), 256, 0, stream>>>(Abuf, w_gate, w_up, hidden, counts, offs, tdesc, ndesc);
  moeB_mfma<<<dim3(32, 24), 256, 0, stream>>>(hidden, w_down, moe_out, counts, offs, tok_list, gate_list, tdesc, ndesc);
  // 8. final
  final_kernel<<<(BB*SS*DD + 1 + 255)/256, 256, 0, stream>>>(x1, moe_out, out, counts, sumP);
}

// Round 23
// 514.460 us; speedup vs baseline: 1.1009x; 1.1009x over previous
//
#include <hip/hip_runtime.h>
#include <hip/hip_bf16.h>

typedef __hip_bfloat16 bf16;

#define BB 2
#define SS 1024
#define DD 1024
#define GG 8
#define HH 2
#define HDIM 64
#define EE 8
#define KTOP 2
#define FFD 4096
#define NTOK (BB*SS)          // 2048
#define NSEL (NTOK*KTOP)      // 4096

typedef __attribute__((ext_vector_type(8))) short bf16x8v;
typedef __attribute__((ext_vector_type(4))) float f32x4;
typedef __attribute__((ext_vector_type(4))) unsigned int u32x4;
typedef __attribute__((ext_vector_type(2))) unsigned int u32x2;

union FragU { uint32_t u[4]; bf16x8v v; };
union FragQ { u32x4 q; bf16x8v v; };

__device__ __forceinline__ float b2f(bf16 v){ return __bfloat162float(v); }
__device__ __forceinline__ bf16  f2b(float v){ return __float2bfloat16(v); }
__device__ __forceinline__ uint32_t f2bu(float f){
  union { bf16 b; unsigned short u; } c; c.b = __float2bfloat16(f); return (uint32_t)c.u;
}
__device__ __forceinline__ uint32_t packbf(float lo, float hi){
  return f2bu(lo) | (f2bu(hi) << 16);
}

// ---------------- RMSNorm -> f32 out ----------------
__global__ void rmsnorm_kernel(const float* __restrict__ x, const float* __restrict__ w,
                               float* __restrict__ out){
  int row = blockIdx.x, tid = threadIdx.x;
  const float* xr = x + (size_t)row * DD;
  float v0 = xr[tid];
  float v1 = xr[tid+256];
  float v2 = xr[tid+512];
  float v3 = xr[tid+768];
  float ss = v0*v0+v1*v1+v2*v2+v3*v3;
  for (int off=32; off; off>>=1) ss += __shfl_down(ss, off);
  __shared__ float red[4];
  if ((tid&63)==0) red[tid>>6]=ss;
  __syncthreads();
  float inv = rsqrtf((red[0]+red[1]+red[2]+red[3])*(1.0f/DD) + 1e-6f);
  float* orow = out + (size_t)row*DD;
  orow[tid]     = v0*inv*w[tid];
  orow[tid+256] = v1*inv*w[tid+256];
  orow[tid+512] = v2*inv*w[tid+512];
  orow[tid+768] = v3*inv*w[tid+768];
}

// ---------------- RMSNorm -> bf16 out (norm1, feeds qkv MFMA) ----------------
__global__ void rmsnorm_b16_kernel(const float* __restrict__ x, const float* __restrict__ w,
                                   bf16* __restrict__ out){
  int row = blockIdx.x, tid = threadIdx.x;
  const float* xr = x + (size_t)row * DD;
  float v0 = xr[tid];
  float v1 = xr[tid+256];
  float v2 = xr[tid+512];
  float v3 = xr[tid+768];
  float ss = v0*v0+v1*v1+v2*v2+v3*v3;
  for (int off=32; off; off>>=1) ss += __shfl_down(ss, off);
  __shared__ float red[4];
  if ((tid&63)==0) red[tid>>6]=ss;
  __syncthreads();
  float inv = rsqrtf((red[0]+red[1]+red[2]+red[3])*(1.0f/DD) + 1e-6f);
  bf16* orow = out + (size_t)row*DD;
  orow[tid]     = f2b(v0*inv*w[tid]);
  orow[tid+256] = f2b(v1*inv*w[tid+256]);
  orow[tid+512] = f2b(v2*inv*w[tid+512]);
  orow[tid+768] = f2b(v3*inv*w[tid+768]);
}

// ---------------- QKV projection (MFMA GEMM M=2048,N=2048,K=1024) ----------------
// Transposed LDS: Bt[col][kp], b128 frag reads. (round-14 proven form)
__global__ void __launch_bounds__(256) qkv_mfma(const bf16* __restrict__ hxb,
      const float* __restrict__ Wq, const float* __restrict__ Wk, const float* __restrict__ Wv,
      float* __restrict__ q, float* __restrict__ k, bf16* __restrict__ vb){
  int mtile = blockIdx.x;
  int nt = blockIdx.y;
  int g = nt >> 2, sub = nt & 3;
  const float* wsrc; int ld;
  if (sub < 2){ wsrc = Wq + (size_t)g*DD*128 + sub*64; ld = 128; }
  else if (sub == 2){ wsrc = Wk + (size_t)g*DD*64; ld = 64; }
  else { wsrc = Wv + (size_t)g*DD*64; ld = 64; }

  __shared__ __attribute__((aligned(16))) uint32_t Bt[64][20];
  int tid = threadIdx.x;
  int w = tid >> 6, l = tid & 63, lg = l >> 4, lr = l & 15;
  int wm = (w >> 1)*32, wn = (w & 1)*32;

  const bf16* arow[2];
  #pragma unroll
  for (int mf=0; mf<2; mf++)
    arow[mf] = hxb + (size_t)(mtile*64 + wm + mf*16 + lr)*DD;

  int scol = tid & 63, skp = tid >> 6;

  f32x4 acc[2][2];
  #pragma unroll
  for (int mf=0;mf<2;mf++)
    #pragma unroll
    for (int nf=0;nf<2;nf++) acc[mf][nf] = (f32x4){0,0,0,0};

  float gld[8];
  #pragma unroll
  for (int jj=0;jj<8;jj++) gld[jj] = wsrc[(size_t)(8*skp + jj)*ld + scol];

  for (int kb=0; kb<DD; kb+=32){
    __syncthreads();
    uint32_t pk[4];
    #pragma unroll
    for (int j2=0;j2<4;j2++) pk[j2] = packbf(gld[2*j2], gld[2*j2+1]);
    *(u32x4*)&Bt[scol][4*skp] = (u32x4){pk[0],pk[1],pk[2],pk[3]};
    __syncthreads();
    if (kb + 32 < DD){
      #pragma unroll
      for (int jj=0;jj<8;jj++) gld[jj] = wsrc[(size_t)(kb + 32 + 8*skp + jj)*ld + scol];
    }
    bf16x8v af[2];
    #pragma unroll
    for (int mf=0;mf<2;mf++)
      af[mf] = *(const bf16x8v*)(arow[mf] + kb + lg*8);
    #pragma unroll
    for (int nf=0;nf<2;nf++){
      FragQ bfr;
      bfr.q = *(const u32x4*)&Bt[wn + nf*16 + lr][lg*4];
      #pragma unroll
      for (int mf=0;mf<2;mf++)
        acc[mf][nf] = __builtin_amdgcn_mfma_f32_16x16x32_bf16(af[mf], bfr.v, acc[mf][nf], 0,0,0);
    }
  }
  #pragma unroll
  for (int mf=0;mf<2;mf++){
    #pragma unroll
    for (int nf=0;nf<2;nf++){
      #pragma unroll
      for (int r=0;r<4;r++){
        int token = mtile*64 + wm + mf*16 + lg*4 + r;
        int b = token >> 10, s = token & (SS-1);
        int c = wn + nf*16 + lr;
        float val = acc[mf][nf][r];
        if (sub < 2)       q[(((size_t)(b*GG+g)*HH + sub)*SS + s)*HDIM + c] = val;
        else if (sub == 2) k[(((size_t)(b*GG+g))*SS + s)*HDIM + c] = val;
        else               vb[(((size_t)(b*GG+g))*SS + s)*HDIM + c] = f2b(val);
      }
    }
  }
}

// ---------------- RoPE f32 -> bf16 ----------------
__global__ void rope_cast_kernel(const float* __restrict__ pin, bf16* __restrict__ pout, int nrows){
  int idx = blockIdx.x*256 + threadIdx.x;
  if (idx >= nrows*32) return;
  int r = idx >> 5, i = idx & 31;
  int s = r & (SS-1);
  float inv = expf(-9.210340371976184f * (float)i / 32.0f); // 10000^(-i/32)
  float ang = (float)s * inv;
  float sn = sinf(ang), cs = cosf(ang);
  const float* row = pin + (size_t)r * HDIM;
  float a = row[i], b = row[i+32];
  pout[(size_t)r*HDIM + i]      = f2b(a*cs - b*sn);
  pout[(size_t)r*HDIM + i + 32] = f2b(a*sn + b*cs);
}

// ---------------- Flash attention (MFMA, causal) + residual -> x1 ----------------
__global__ void __launch_bounds__(256) attn_mfma(
    const bf16* __restrict__ qb, const bf16* __restrict__ kb, const bf16* __restrict__ vb,
    const float* __restrict__ x, float* __restrict__ x1){
  int qt = blockIdx.x;
  int bh = blockIdx.y;
  int b = bh >> 4, gh = bh & 15;
  int bg = b*GG + (gh >> 1);
  int q0 = qt * 64;

  int tid = threadIdx.x;
  int w = tid >> 6, l = tid & 63, lg = l >> 4, lr = l & 15;

  __shared__ uint32_t Vp[32][68];
  __shared__ uint32_t Plu[4][16][33];

  const bf16* qbase = qb + ((size_t)bh*SS + q0 + w*16 + lr)*HDIM;
  bf16x8v qfr[2];
  qfr[0] = *(const bf16x8v*)(qbase + lg*8);
  qfr[1] = *(const bf16x8v*)(qbase + 32 + lg*8);

  f32x4 O[4];
  #pragma unroll
  for (int i=0;i<4;i++) O[i] = (f32x4){0,0,0,0};
  float mrow[4] = {-3e38f,-3e38f,-3e38f,-3e38f};
  float lrow[4] = {0.f,0.f,0.f,0.f};

  const bf16* kbg = kb + (size_t)bg*SS*HDIM;
  const unsigned short* vbg = (const unsigned short*)(vb + (size_t)bg*SS*HDIM);

  int c44 = (tid & 15)*4;
  int kpq = tid >> 4;

  for (int t=0; t<=qt; t++){
    int kv0 = t*64;
    __syncthreads();
    #pragma unroll
    for (int it=0; it<2; it++){
      int kp = kpq + it*16;
      const unsigned short* r0 = vbg + (size_t)(kv0 + 2*kp)*HDIM + c44;
      ushort4 a = *(const ushort4*)r0;
      ushort4 bq = *(const ushort4*)(r0 + HDIM);
      Vp[kp][c44+0] = (uint32_t)a.x | ((uint32_t)bq.x<<16);
      Vp[kp][c44+1] = (uint32_t)a.y | ((uint32_t)bq.y<<16);
      Vp[kp][c44+2] = (uint32_t)a.z | ((uint32_t)bq.z<<16);
      Vp[kp][c44+3] = (uint32_t)a.w | ((uint32_t)bq.w<<16);
    }
    __syncthreads();

    f32x4 sacc[4];
    #pragma unroll
    for (int nf=0;nf<4;nf++){
      sacc[nf] = (f32x4){0,0,0,0};
      const bf16* kr = kbg + (size_t)(kv0 + nf*16 + lr)*HDIM + lg*8;
      bf16x8v kf0 = *(const bf16x8v*)kr;
      bf16x8v kf1 = *(const bf16x8v*)(kr + 32);
      sacc[nf] = __builtin_amdgcn_mfma_f32_16x16x32_bf16(qfr[0], kf0, sacc[nf], 0,0,0);
      sacc[nf] = __builtin_amdgcn_mfma_f32_16x16x32_bf16(qfr[1], kf1, sacc[nf], 0,0,0);
    }

    bool diag = (t == qt);
    float p[4][4];
    float rmax[4] = {-3e38f,-3e38f,-3e38f,-3e38f};
    #pragma unroll
    for (int nf=0;nf<4;nf++){
      #pragma unroll
      for (int r=0;r<4;r++){
        float s = sacc[nf][r]*0.125f;
        if (diag && (nf*16+lr > w*16+lg*4+r)) s = -3e38f;
        p[nf][r] = s;
        rmax[r] = fmaxf(rmax[r], s);
      }
    }
    #pragma unroll
    for (int r=0;r<4;r++){
      #pragma unroll
      for (int mm=1; mm<16; mm<<=1) rmax[r] = fmaxf(rmax[r], __shfl_xor(rmax[r], mm));
      float mn = fmaxf(mrow[r], rmax[r]);
      float resc = __expf(mrow[r]-mn);
      mrow[r] = mn;
      float rsum = 0.f;
      #pragma unroll
      for (int nf=0;nf<4;nf++){
        float e = __expf(p[nf][r]-mn);
        p[nf][r] = e;
        rsum += e;
      }
      #pragma unroll
      for (int mm=1; mm<16; mm<<=1) rsum += __shfl_xor(rsum, mm);
      lrow[r] = lrow[r]*resc + rsum;
      O[0][r]*=resc; O[1][r]*=resc; O[2][r]*=resc; O[3][r]*=resc;
    }

    #pragma unroll
    for (int nf=0;nf<4;nf++){
      #pragma unroll
      for (int r=0;r<4;r++){
        float pnbr = __shfl_xor(p[nf][r], 1);
        if ((lr & 1) == 0)
          Plu[w][lg*4+r][(nf*16+lr)>>1] = packbf(p[nf][r], pnbr);
      }
    }

    #pragma unroll
    for (int kc=0;kc<2;kc++){
      FragU pa;
      #pragma unroll
      for (int jp=0;jp<4;jp++)
        pa.u[jp] = Plu[w][lr][kc*16 + lg*4 + jp];
      #pragma unroll
      for (int nf=0;nf<4;nf++){
        FragU vf;
        #pragma unroll
        for (int jp=0;jp<4;jp++) vf.u[jp] = Vp[kc*16 + lg*4 + jp][nf*16 + lr];
        O[nf] = __builtin_amdgcn_mfma_f32_16x16x32_bf16(pa.v, vf.v, O[nf], 0,0,0);
      }
    }
  }

  #pragma unroll
  for (int r=0;r<4;r++){
    int s = q0 + w*16 + lg*4 + r;
    float inv = 1.f/fmaxf(lrow[r], 1e-30f);
    size_t rowo = ((size_t)(b*SS + s))*DD + gh*HDIM;
    #pragma unroll
    for (int nf=0;nf<4;nf++){
      size_t oi = rowo + nf*16 + lr;
      x1[oi] = x[oi] + O[nf][r]*inv;
    }
  }
}

// ---------------- Router: logits, softmax, top-2; probs to buffer (NO atomics) ----------------
__global__ void router_kernel(const float* __restrict__ h2, const float* __restrict__ rw,
                              int* __restrict__ topi, float* __restrict__ topv,
                              float* __restrict__ probs){
  int token = blockIdx.x, tid = threadIdx.x;
  const float* hr = h2 + (size_t)token * DD;
  float part[EE];
  #pragma unroll
  for (int e=0;e<EE;e++) part[e]=0.f;
  for (int d = tid; d < DD; d += 256) {
    float hv = hr[d];
    #pragma unroll
    for (int e=0;e<EE;e++) part[e] += hv * rw[d*EE+e];
  }
  #pragma unroll
  for (int e=0;e<EE;e++)
    for (int off=32; off; off>>=1) part[e] += __shfl_down(part[e], off);
  __shared__ float red[4][EE];
  if ((tid&63)==0){
    #pragma unroll
    for (int e=0;e<EE;e++) red[tid>>6][e]=part[e];
  }
  __syncthreads();
  if (tid==0){
    float lg[EE];
    #pragma unroll
    for (int e=0;e<EE;e++) lg[e]=red[0][e]+red[1][e]+red[2][e]+red[3][e];
    float m = lg[0];
    #pragma unroll
    for (int e=1;e<EE;e++) m = fmaxf(m, lg[e]);
    float ex[EE], ssum=0.f;
    #pragma unroll
    for (int e=0;e<EE;e++){ ex[e]=expf(lg[e]-m); ssum+=ex[e]; }
    float p[EE];
    #pragma unroll
    for (int e=0;e<EE;e++){ p[e]=ex[e]/ssum; probs[token*EE+e]=p[e]; }
    int i1=0;
    for (int e=1;e<EE;e++) if (p[e]>p[i1]) i1=e;
    int i2=-1;
    for (int e=0;e<EE;e++) if (e!=i1 && (i2<0 || p[e]>p[i2])) i2=e;
    float g1=p[i1], g2=p[i2], gs=g1+g2;
    topi[token*2]=i1; topi[token*2+1]=i2;
    topv[token*2]=g1/gs; topv[token*2+1]=g2/gs;
  }
}

// ---------------- Stats: reduce probs -> sumP, topi -> counts (1 block) ----------------
__global__ void stats_kernel(const float* __restrict__ probs, const int* __restrict__ topi,
                             float* __restrict__ sumP, int* __restrict__ counts){
  int tid = threadIdx.x;      // 256
  float ls[EE];
  int lc[EE];
  #pragma unroll
  for (int e=0;e<EE;e++){ ls[e]=0.f; lc[e]=0; }
  for (int t = tid; t < NTOK; t += 256){
    const float* pr = probs + (size_t)t*EE;
    #pragma unroll
    for (int e=0;e<EE;e++) ls[e] += pr[e];
    lc[topi[2*t]]++;
    lc[topi[2*t+1]]++;
  }
  #pragma unroll
  for (int e=0;e<EE;e++){
    for (int off=32; off; off>>=1){
      ls[e] += __shfl_down(ls[e], off);
      lc[e] += __shfl_down(lc[e], off);
    }
  }
  __shared__ float rs[4][EE];
  __shared__ int   rc[4][EE];
  if ((tid&63)==0){
    #pragma unroll
    for (int e=0;e<EE;e++){ rs[tid>>6][e]=ls[e]; rc[tid>>6][e]=lc[e]; }
  }
  __syncthreads();
  if (tid==0){
    #pragma unroll
    for (int e=0;e<EE;e++){
      sumP[e]   = rs[0][e]+rs[1][e]+rs[2][e]+rs[3][e];
      counts[e] = rc[0][e]+rc[1][e]+rc[2][e]+rc[3][e];
    }
  }
}

// ---------------- Deterministic routing fill + tile-descriptor table ----------------
__global__ void fill_kernel(const int* __restrict__ topi, const float* __restrict__ topv,
                            const int* __restrict__ counts, int* __restrict__ offs,
                            int* __restrict__ tok_list, float* __restrict__ gate_list,
                            int* __restrict__ tdesc, int* __restrict__ ndesc){
  int tid = threadIdx.x;        // 512 = 8 waves
  int w = tid >> 6, lane = tid & 63;
  if (tid < EE){
    int o = 0;
    for (int e=0;e<tid;e++) o += counts[e];
    offs[tid] = o;
  }
  if (tid == 0){
    int n = 0;
    for (int e=0;e<EE;e++){
      int t = (counts[e] + 255) >> 8;
      for (int m=0;m<t;m++) tdesc[n++] = e | (m << 8);
    }
    *ndesc = n;
  }
  int pos = 0;
  for (int e=0;e<w;e++) pos += counts[e];
  for (int j0=0; j0<NSEL; j0+=64){
    int j = j0 + lane;
    bool hit = (topi[j] == w);
    unsigned long long mask = __ballot(hit);
    if (hit){
      int idx = pos + __popcll(mask & ((1ull<<lane)-1ull));
      tok_list[idx] = j >> 1;
      gate_list[idx] = topv[j];
    }
    pos += __popcll(mask);
  }
}

// ---------------- Gather routed activations to bf16 A matrix (float4 vectorized) ----------------
__global__ void gather_kernel(const float* __restrict__ h2, const int* __restrict__ tok_list,
                              bf16* __restrict__ Abuf){
  int i = blockIdx.x*256 + threadIdx.x;      // over NSEL*DD/4
  int pos = i >> 8, d4 = (i & 255) * 4;
  int tok = tok_list[pos];
  float4 v = *(const float4*)&h2[(size_t)tok*DD + d4];
  u32x2 pk = (u32x2){ packbf(v.x, v.y), packbf(v.z, v.w) };
  *(u32x2*)&Abuf[(size_t)pos*DD + d4] = pk;
}

// ---------------- MoE phase A (MFMA): hidden = silu(A@Wg)*(A@Wu) ----------------
// Round-14 proven form: BM=256, BN=64, BK=32, transposed LDS [col][20], b128 frag
// reads, scalar-staged weights with 1-deep register prefetch.
__global__ void __launch_bounds__(256, 2) moeA_mfma(const bf16* __restrict__ Abuf,
                            const float* __restrict__ wg, const float* __restrict__ wu,
                            bf16* __restrict__ hidden,
                            const int* __restrict__ counts, const int* __restrict__ offs,
                            const int* __restrict__ tdesc, const int* __restrict__ ndesc){
  int ti = blockIdx.y;
  if (ti >= *ndesc) return;
  int d = tdesc[ti];
  int e = d & 255, mtile = d >> 8;
  int cnt = counts[e];
  int ntile = blockIdx.x;
  int offs_e = offs[e];
  int ncol0 = ntile*64;

  __shared__ __attribute__((aligned(16))) uint32_t Bg[64][20];
  __shared__ __attribute__((aligned(16))) uint32_t Bu[64][20];

  int tid = threadIdx.x;
  int w = tid >> 6, l = tid & 63, lg = l >> 4, lr = l & 15;
  int wm = w*64;

  const bf16* arow[4];
  #pragma unroll
  for (int mf=0; mf<4; mf++){
    int slot = mtile*256 + wm + mf*16 + lr;
    if (slot >= cnt) slot = cnt - 1;
    arow[mf] = Abuf + (size_t)(offs_e + slot)*DD;
  }

  const float* wgb = wg + (size_t)e*DD*FFD + ncol0;
  const float* wub = wu + (size_t)e*DD*FFD + ncol0;
  int scol = tid & 63, skp = tid >> 6;   // staging col, kp-group (kp = 4*skp+j2)

  f32x4 acc_g[4][4], acc_u[4][4];
  #pragma unroll
  for (int mf=0; mf<4; mf++)
    #pragma unroll
    for (int nf=0; nf<4; nf++){ acc_g[mf][nf] = (f32x4){0,0,0,0}; acc_u[mf][nf] = (f32x4){0,0,0,0}; }

  float gld[8], uld[8];
  #pragma unroll
  for (int jj=0;jj<8;jj++){
    gld[jj] = wgb[(size_t)(8*skp + jj)*FFD + scol];
    uld[jj] = wub[(size_t)(8*skp + jj)*FFD + scol];
  }

  for (int kb=0; kb<DD; kb+=32){
    __syncthreads();
    {
      uint32_t pg[4], pu[4];
      #pragma unroll
      for (int j2=0;j2<4;j2++){
        pg[j2] = packbf(gld[2*j2], gld[2*j2+1]);
        pu[j2] = packbf(uld[2*j2], uld[2*j2+1]);
      }
      *(u32x4*)&Bg[scol][4*skp] = (u32x4){pg[0],pg[1],pg[2],pg[3]};
      *(u32x4*)&Bu[scol][4*skp] = (u32x4){pu[0],pu[1],pu[2],pu[3]};
    }
    __syncthreads();
    if (kb + 32 < DD){
      #pragma unroll
      for (int jj=0;jj<8;jj++){
        gld[jj] = wgb[(size_t)(kb + 32 + 8*skp + jj)*FFD + scol];
        uld[jj] = wub[(size_t)(kb + 32 + 8*skp + jj)*FFD + scol];
      }
    }
    bf16x8v afr[4];
    #pragma unroll
    for (int mf=0; mf<4; mf++)
      afr[mf] = *(const bf16x8v*)(arow[mf] + kb + lg*8);
    #pragma unroll
    for (int nf=0; nf<4; nf++){
      int col = nf*16 + lr;
      FragQ fg, fu;
      fg.q = *(const u32x4*)&Bg[col][lg*4];
      fu.q = *(const u32x4*)&Bu[col][lg*4];
      #pragma unroll
      for (int mf=0; mf<4; mf++){
        acc_g[mf][nf] = __builtin_amdgcn_mfma_f32_16x16x32_bf16(afr[mf], fg.v, acc_g[mf][nf], 0,0,0);
        acc_u[mf][nf] = __builtin_amdgcn_mfma_f32_16x16x32_bf16(afr[mf], fu.v, acc_u[mf][nf], 0,0,0);
      }
    }
  }
  #pragma unroll
  for (int mf=0; mf<4; mf++){
    #pragma unroll
    for (int ri=0; ri<4; ri++){
      int slot = mtile*256 + wm + mf*16 + lg*4 + ri;
      if (slot < cnt){
        bf16* hrow = hidden + (size_t)(offs_e + slot)*FFD + ncol0;
        #pragma unroll
        for (int nf=0; nf<4; nf++){
          float gv = acc_g[mf][nf][ri];
          float uv = acc_u[mf][nf][ri];
          float act = gv / (1.f + expf(-gv)) * uv;
          hrow[nf*16 + lr] = f2b(act);
        }
      }
    }
  }
}

// ---------------- MoE phase B (MFMA): moe_out += gate * hidden @ Wd ----------------
// Round-14 proven form: BM=256, BN=128, 4-way K-split, transposed LDS [col][20].
__global__ void __launch_bounds__(256, 2) moeB_mfma(const bf16* __restrict__ hidden,
                            const float* __restrict__ wd, float* __restrict__ moe_out,
                            const int* __restrict__ counts, const int* __restrict__ offs,
                            const int* __restrict__ tok_list, const float* __restrict__ gate_list,
                            const int* __restrict__ tdesc, const int* __restrict__ ndesc){
  int ti = blockIdx.y;
  if (ti >= *ndesc) return;
  int d = tdesc[ti];
  int e = d & 255, mtile = d >> 8;
  int cnt = counts[e];
  int ntile = blockIdx.x & 7;
  int kchunk = blockIdx.x >> 3;
  int offs_e = offs[e];
  int ncol0 = ntile*128;
  int kb0 = kchunk*1024;

  __shared__ __attribute__((aligned(16))) uint32_t Bd[128][20];

  int tid = threadIdx.x;
  int w = tid >> 6, l = tid & 63, lg = l >> 4, lr = l & 15;
  int wm = w*64;

  const bf16* arow[4];
  #pragma unroll
  for (int mf=0; mf<4; mf++){
    int slot = mtile*256 + wm + mf*16 + lr;
    if (slot >= cnt) slot = cnt - 1;
    arow[mf] = hidden + (size_t)(offs_e + slot)*FFD + kb0;
  }

  const float* wdb = wd + (size_t)e*FFD*DD + (size_t)kb0*DD + ncol0;
  int scol = tid & 127, shalf = tid >> 7;   // staging col, kp half (kp = 8*shalf + j2)

  f32x4 acc[4][8];
  #pragma unroll
  for (int mf=0; mf<4; mf++)
    #pragma unroll
    for (int nf=0; nf<8; nf++) acc[mf][nf] = (f32x4){0,0,0,0};

  float dld[16];
  #pragma unroll
  for (int jj=0;jj<16;jj++) dld[jj] = wdb[(size_t)(16*shalf + jj)*DD + scol];

  for (int kb=0; kb<1024; kb+=32){
    __syncthreads();
    {
      uint32_t pk[8];
      #pragma unroll
      for (int j2=0;j2<8;j2++) pk[j2] = packbf(dld[2*j2], dld[2*j2+1]);
      *(u32x4*)&Bd[scol][8*shalf]     = (u32x4){pk[0],pk[1],pk[2],pk[3]};
      *(u32x4*)&Bd[scol][8*shalf + 4] = (u32x4){pk[4],pk[5],pk[6],pk[7]};
    }
    __syncthreads();
    if (kb + 32 < 1024){
      #pragma unroll
      for (int jj=0;jj<16;jj++) dld[jj] = wdb[(size_t)(kb + 32 + 16*shalf + jj)*DD + scol];
    }
    bf16x8v afr[4];
    #pragma unroll
    for (int mf=0; mf<4; mf++)
      afr[mf] = *(const bf16x8v*)(arow[mf] + kb + lg*8);
    #pragma unroll
    for (int nf=0; nf<8; nf++){
      int col = nf*16 + lr;
      FragQ fd;
      fd.q = *(const u32x4*)&Bd[col][lg*4];
      #pragma unroll
      for (int mf=0; mf<4; mf++)
        acc[mf][nf] = __builtin_amdgcn_mfma_f32_16x16x32_bf16(afr[mf], fd.v, acc[mf][nf], 0,0,0);
    }
  }
  #pragma unroll
  for (int mf=0; mf<4; mf++){
    #pragma unroll
    for (int ri=0; ri<4; ri++){
      int slot = mtile*256 + wm + mf*16 + lg*4 + ri;
      if (slot < cnt){
        int pos = offs_e + slot;
        int tok = tok_list[pos];
        float gate = gate_list[pos];
        float* orow = moe_out + (size_t)tok*DD + ncol0;
        #pragma unroll
        for (int nf=0; nf<8; nf++)
          atomicAdd(&orow[nf*16 + lr], gate * acc[mf][nf][ri]);
      }
    }
  }
}

// ---------------- Final: out = x1 + moe_out (float4), + aux ----------------
__global__ void final_kernel(const float* __restrict__ x1, const float* __restrict__ moe,
                             float* __restrict__ out,
                             const int* __restrict__ counts, const float* __restrict__ sumP){
  int i = blockIdx.x*256 + threadIdx.x;
  int n4 = (BB*SS*DD) / 4;
  if (i < n4) {
    float4 a = *(const float4*)&x1[(size_t)i*4];
    float4 m = *(const float4*)&moe[(size_t)i*4];
    float4 o;
    o.x = a.x + m.x; o.y = a.y + m.y; o.z = a.z + m.z; o.w = a.w + m.w;
    *(float4*)&out[(size_t)i*4] = o;
  } else if (i == n4) {
    float aux = 0.f;
    for (int e=0;e<EE;e++)
      aux += ((float)counts[e] / (float)(BB*SS*KTOP)) * (sumP[e] / (float)(BB*SS));
    out[BB*SS*DD] = aux * (float)EE;
  }
}

extern "C" void kernel_launch(void* const* d_in, const int* in_sizes, int n_in,
                              void* d_out, int out_size, void* d_ws, size_t ws_size,
                              hipStream_t stream) {
  const float* x        = (const float*)d_in[0];
  const float* norm1_w  = (const float*)d_in[1];
  const float* Wq       = (const float*)d_in[2];
  const float* Wk       = (const float*)d_in[3];
  const float* Wv       = (const float*)d_in[4];
  const float* norm2_w  = (const float*)d_in[5];
  const float* router_w = (const float*)d_in[6];
  const float* w_gate   = (const float*)d_in[7];
  const float* w_up     = (const float*)d_in[8];
  const float* w_down   = (const float*)d_in[9];
  float* out = (float*)d_out;

  float* ws = (float*)d_ws;
  // word offsets (f32 words) — total 20,987,936 words = 83.95 MB (proven footprint)
  bf16*  hxb     = (bf16*)ws;                     // [0 .. 1,048,576)        2048x1024 bf16
  float* qf      = ws + 1048576;                  // [1,048,576 .. 3,145,728)  32768x64 f32
  float* kf      = ws + 3145728;                  // [3,145,728 .. 4,194,304)  16384x64 f32
  bf16*  qbb     = (bf16*)(ws + 4194304);         // [4,194,304 .. 5,242,880)  32768x64 bf16
  bf16*  kbb     = (bf16*)(ws + 5242880);         // [5,242,880 .. 5,767,168)  16384x64 bf16
  bf16*  vbb     = (bf16*)(ws + 5767168);         // [5,767,168 .. 6,291,456)  16384x64 bf16
  float* x1      = ws + 6291456;                  // [6,291,456 .. 8,388,608)
  float* h2      = ws + 8388608;                  // [8,388,608 .. 10,485,760)
  float* moe_out = ws + 10485760;                 // [10,485,760 .. 12,582,912)
  int*   counts  = (int*)(ws + 12582912);         // 8
  float* sumP    = ws + 12582920;                 // 8
  int*   offs    = (int*)(ws + 12582928);         // 8 (+pad)
  int*   topi    = (int*)(ws + 12582944);         // 4096
  float* topv    = ws + 12587040;                 // 4096
  int*   tok_list= (int*)(ws + 12591136);         // 4096
  float* gate_list = ws + 12595232;               // 4096
  bf16*  hidden  = (bf16*)(ws + 12599328);        // 4096x4096 bf16 -> ends 20,987,936
  bf16*  Abuf    = (bf16*)ws;                     // words [0..2,097,152); aliases hxb+qf[:half], dead
  int*   tdesc   = (int*)(ws + 3145728);          // 24 ints in dead kf region
  int*   ndesc   = (int*)(ws + 3145728 + 24);     // 1 int
  float* probs   = ws + 3145728 + 32;             // 2048x8 f32 = 16384 words, in dead kf region

  hipMemsetAsync(moe_out, 0, (size_t)BB*SS*DD*sizeof(float), stream);

  // 1. norm1 -> bf16
  rmsnorm_b16_kernel<<<NTOK, 256, 0, stream>>>(x, norm1_w, hxb);
  // 2. qkv MFMA (writes f32 q/k, bf16 v)
  qkv_mfma<<<dim3(32, 32), 256, 0, stream>>>(hxb, Wq, Wk, Wv, qf, kf, vbb);
  // 3. rope + cast to bf16
  rope_cast_kernel<<<(BB*GG*HH*SS*32)/256, 256, 0, stream>>>(qf, qbb, BB*GG*HH*SS);
  rope_cast_kernel<<<(BB*GG*SS*32)/256, 256, 0, stream>>>(kf, kbb, BB*GG*SS);
  // 4. flash attention + residual
  attn_mfma<<<dim3(SS/64, BB*GG*HH), 256, 0, stream>>>(qbb, kbb, vbb, x, x1);
  // 5. norm2
  rmsnorm_kernel<<<NTOK, 256, 0, stream>>>(x1, norm2_w, h2);
  // 6. router (no atomics) + stats reduction + routing tables
  router_kernel<<<NTOK, 256, 0, stream>>>(h2, router_w, topi, topv, probs);
  stats_kernel<<<1, 256, 0, stream>>>(probs, topi, sumP, counts);
  fill_kernel<<<1, 512, 0, stream>>>(topi, topv, counts, offs, tok_list, gate_list, tdesc, ndesc);
  // 7. MoE (MFMA grouped GEMM, BM=256, compacted tile grid; round-14 proven kernels)
  gather_kernel<<<(NSEL*DD/4)/256, 256, 0, stream>>>(h2, tok_list, Abuf);
  moeA_mfma<<<dim3(64, 24), 256, 0, stream>>>(Abuf, w_gate, w_up, hidden, counts, offs, tdesc, ndesc);
  moeB_mfma<<<dim3(32, 24), 256, 0, stream>>>(hidden, w_down, moe_out, counts, offs, tok_list, gate_list, tdesc, ndesc);
  // 8. final (float4)
  final_kernel<<<((BB*SS*DD)/4 + 1 + 255)/256, 256, 0, stream>>>(x1, moe_out, out, counts, sumP);
}